// Round 1
// baseline (728.569 us; speedup 1.0000x reference)
//
#include <hip/hip_runtime.h>
#include <math.h>

typedef __bf16 bf16_t;
typedef __bf16 bf16x8 __attribute__((ext_vector_type(8)));
typedef __bf16 bf16x4v __attribute__((ext_vector_type(4)));
typedef float f32x4 __attribute__((ext_vector_type(4)));

#define MFMA16x16(a, b, c) __builtin_amdgcn_mfma_f32_16x16x32_bf16((a), (b), (c), 0, 0, 0)

#define MASK_VAL -1000.0f
#define EXP_SHIFT 20.0f

// ---------------- prep kernels ----------------

// qin[m][e] = bf16(query[m][e] + pe(s, e)), m = s*4+b, layout matches query (S,B,E) flat
__global__ __launch_bounds__(256) void prep_qpe(const float* __restrict__ query,
                                                bf16_t* __restrict__ qin) {
    int idx = blockIdx.x * 256 + threadIdx.x;   // 524288 threads: (s, i) pairs
    int s = idx >> 8;
    int i = idx & 255;
    int e = i * 2;
    const float C = 9.210340371976184f / 512.0f;  // ln(10000)/512
    float freq = __expf(-(float)e * C);
    float ang = (float)s * freq;
    float sv, cv;
    sincosf(ang, &sv, &cv);
    #pragma unroll
    for (int b = 0; b < 4; b++) {
        int base = ((s * 4 + b) << 9) + e;
        qin[base]     = (bf16_t)(query[base] + sv);
        qin[base + 1] = (bf16_t)(query[base + 1] + cv);
    }
}

__global__ __launch_bounds__(256) void prep_kcast(const float* __restrict__ key,
                                                  bf16_t* __restrict__ kin) {
    int idx = blockIdx.x * 256 + threadIdx.x;   // 1048576 threads, 4 elems each
    float4 v = ((const float4*)key)[idx];
    bf16x4v o;
    o.x = (bf16_t)v.x; o.y = (bf16_t)v.y; o.z = (bf16_t)v.z; o.w = (bf16_t)v.w;
    ((bf16x4v*)kin)[idx] = o;
}

// Transposed bf16 weight slices: wqt[j][e] = Wq[e][j] (j in [0,256)),
//                                wkt[j][e] = Wk[e][256+j]
__global__ __launch_bounds__(256) void prep_wt(const float* __restrict__ Wq,
                                               const float* __restrict__ Wk,
                                               bf16_t* __restrict__ wqt,
                                               bf16_t* __restrict__ wkt) {
    int idx = blockIdx.x * 256 + threadIdx.x;   // 262144 threads
    int t = idx & 131071;
    int j = t >> 9, e = t & 511;
    if (idx < 131072) wqt[t] = (bf16_t)Wq[e * 544 + j];
    else              wkt[t] = (bf16_t)Wk[e * 544 + 256 + j];
}

// OR-reduce masks into a flag (so the all-False case takes a branch-free fast path)
__global__ __launch_bounds__(256) void mask_any(const uint4* __restrict__ am,
                                                const uint4* __restrict__ kpm,
                                                int* __restrict__ flag) {
    int idx = blockIdx.x * 256 + threadIdx.x;
    unsigned int v = 0;
    if (idx < 262144) { uint4 x = am[idx]; v = x.x | x.y | x.z | x.w; }
    else if (idx < 262656) { uint4 x = kpm[idx - 262144]; v = x.x | x.y | x.z | x.w; }
    if (v) atomicOr(flag, 1);
}

// ---------------- projection GEMM ----------------
// C[m][n] = sum_k A[m][k]*Bt[n][k] + bias[n];  M=8192, N=256, K=512
// Output layout: Out[((h*4+b)*2048 + s)*32 + d], m = s*4+b, n = h*32+d  (MFMA-frag-friendly)
__global__ __launch_bounds__(256) void proj_gemm(const bf16_t* __restrict__ A,
                                                 const bf16_t* __restrict__ Bt,
                                                 const float* __restrict__ bias,
                                                 bf16_t* __restrict__ Out) {
    int lane = threadIdx.x & 63;
    int wave = threadIdx.x >> 6;
    int wm = wave & 1, wn = wave >> 1;
    int m0 = blockIdx.x * 64 + wm * 32;
    int n0 = blockIdx.y * 64 + wn * 32;
    int lrow = lane & 15, quad = lane >> 4;
    f32x4 acc00 = {0.f, 0.f, 0.f, 0.f};
    f32x4 acc01 = acc00, acc10 = acc00, acc11 = acc00;
    const bf16_t* Ab = A + (size_t)(m0 + lrow) * 512 + quad * 8;
    const bf16_t* Bb = Bt + (size_t)(n0 + lrow) * 512 + quad * 8;
    #pragma unroll 4
    for (int k0 = 0; k0 < 512; k0 += 32) {
        bf16x8 a0 = *(const bf16x8*)(Ab + k0);
        bf16x8 a1 = *(const bf16x8*)(Ab + 16 * 512 + k0);
        bf16x8 b0 = *(const bf16x8*)(Bb + k0);
        bf16x8 b1 = *(const bf16x8*)(Bb + 16 * 512 + k0);
        acc00 = MFMA16x16(a0, b0, acc00);
        acc01 = MFMA16x16(a0, b1, acc01);
        acc10 = MFMA16x16(a1, b0, acc10);
        acc11 = MFMA16x16(a1, b1, acc11);
    }
    #pragma unroll
    for (int i = 0; i < 2; i++) {
        #pragma unroll
        for (int j = 0; j < 2; j++) {
            f32x4 acc = (i == 0) ? (j == 0 ? acc00 : acc01) : (j == 0 ? acc10 : acc11);
            int col = n0 + j * 16 + lrow;
            float bv = bias[col];
            int h = col >> 5, d = col & 31;
            #pragma unroll
            for (int r = 0; r < 4; r++) {
                int row = m0 + i * 16 + quad * 4 + r;
                int s = row >> 2, bb = row & 3;
                Out[(size_t)((h * 4 + bb) * 2048 + s) * 32 + d] = (bf16_t)(acc[r] + bv);
            }
        }
    }
}

// ---------------- fused scores + softmax ----------------
// grid: (32 q-tiles, 32 hb). Block = 4 waves; each wave owns 16 q rows.
// Pass 1: running max + sum of exp(s - EXP_SHIFT). Pass 2: recompute, write exp(s-M)*INV.
template <bool MASKED>
__device__ __forceinline__ void attn_core(const bf16_t* __restrict__ Qb,
                                          const bf16_t* __restrict__ Kb,
                                          const unsigned char* __restrict__ am,
                                          const unsigned char* __restrict__ kpm,
                                          float* __restrict__ out) {
    int lane = threadIdx.x & 63;
    int wave = threadIdx.x >> 6;
    int hb = blockIdx.y;
    int b = hb & 3;
    int q0 = blockIdx.x * 64 + wave * 16;
    int lrow = lane & 15, quad = lane >> 4;
    // A fragment: Q rows q0..q0+15, lane reads Q[q0+lrow][quad*8 .. +7]
    bf16x8 afrag = *(const bf16x8*)(Qb + (size_t)(hb * 2048 + q0 + lrow) * 32 + quad * 8);
    const bf16_t* kbase = Kb + (size_t)hb * 2048 * 32;

    float m[4] = {-1e30f, -1e30f, -1e30f, -1e30f};
    float l[4] = {0.f, 0.f, 0.f, 0.f};
    #pragma unroll 2
    for (int t0 = 0; t0 < 2048; t0 += 16) {
        bf16x8 bfrag = *(const bf16x8*)(kbase + (size_t)(t0 + lrow) * 32 + quad * 8);
        f32x4 acc = {0.f, 0.f, 0.f, 0.f};
        acc = MFMA16x16(afrag, bfrag, acc);
        int col = t0 + lrow;
        bool kp = MASKED ? (kpm[b * 2048 + col] != 0) : false;
        #pragma unroll
        for (int r = 0; r < 4; r++) {
            float s = acc[r];
            if (MASKED) {
                int row = q0 + quad * 4 + r;
                if (kp || am[(size_t)row * 2048 + col]) s = MASK_VAL;
            }
            m[r] = fmaxf(m[r], s);
            l[r] += __expf(s - EXP_SHIFT);
        }
    }
    // reduce across the 16-lane row group (lanes differing in low 4 bits share rows)
    #pragma unroll
    for (int off = 1; off < 16; off <<= 1) {
        #pragma unroll
        for (int r = 0; r < 4; r++) {
            m[r] = fmaxf(m[r], __shfl_xor(m[r], off));
            l[r] += __shfl_xor(l[r], off);
        }
    }
    float M[4], INV[4];
    bool need = false;
    #pragma unroll
    for (int r = 0; r < 4; r++) need = need || (l[r] == 0.0f) || (m[r] > 80.0f);
    if (__any(need)) {
        // rare stable path (e.g. fully-masked rows or huge scores): recompute sum vs true max
        float l2[4] = {0.f, 0.f, 0.f, 0.f};
        for (int t0 = 0; t0 < 2048; t0 += 16) {
            bf16x8 bfrag = *(const bf16x8*)(kbase + (size_t)(t0 + lrow) * 32 + quad * 8);
            f32x4 acc = {0.f, 0.f, 0.f, 0.f};
            acc = MFMA16x16(afrag, bfrag, acc);
            int col = t0 + lrow;
            bool kp = MASKED ? (kpm[b * 2048 + col] != 0) : false;
            #pragma unroll
            for (int r = 0; r < 4; r++) {
                float s = acc[r];
                if (MASKED) {
                    int row = q0 + quad * 4 + r;
                    if (kp || am[(size_t)row * 2048 + col]) s = MASK_VAL;
                }
                l2[r] += __expf(s - m[r]);
            }
        }
        #pragma unroll
        for (int off = 1; off < 16; off <<= 1) {
            #pragma unroll
            for (int r = 0; r < 4; r++) l2[r] += __shfl_xor(l2[r], off);
        }
        #pragma unroll
        for (int r = 0; r < 4; r++) { M[r] = m[r]; INV[r] = 1.0f / l2[r]; }
    } else {
        #pragma unroll
        for (int r = 0; r < 4; r++) { M[r] = EXP_SHIFT; INV[r] = 1.0f / l[r]; }
    }
    // pass 2: recompute scores, normalize, write
    float* obase = out + (size_t)hb * 2048 * 2048;
    #pragma unroll 2
    for (int t0 = 0; t0 < 2048; t0 += 16) {
        bf16x8 bfrag = *(const bf16x8*)(kbase + (size_t)(t0 + lrow) * 32 + quad * 8);
        f32x4 acc = {0.f, 0.f, 0.f, 0.f};
        acc = MFMA16x16(afrag, bfrag, acc);
        int col = t0 + lrow;
        bool kp = MASKED ? (kpm[b * 2048 + col] != 0) : false;
        #pragma unroll
        for (int r = 0; r < 4; r++) {
            float s = acc[r];
            int row = q0 + quad * 4 + r;
            if (MASKED) {
                if (kp || am[(size_t)row * 2048 + col]) s = MASK_VAL;
            }
            float o = __expf(s - M[r]) * INV[r];
            __builtin_nontemporal_store(o, obase + (size_t)row * 2048 + col);
        }
    }
}

__global__ __launch_bounds__(256) void attn_kernel(const bf16_t* __restrict__ Qb,
                                                   const bf16_t* __restrict__ Kb,
                                                   const unsigned char* __restrict__ am,
                                                   const unsigned char* __restrict__ kpm,
                                                   const int* __restrict__ flag,
                                                   float* __restrict__ out) {
    if (*flag) attn_core<true>(Qb, Kb, am, kpm, out);
    else       attn_core<false>(Qb, Kb, am, kpm, out);
}

// ---------------- launcher ----------------
extern "C" void kernel_launch(void* const* d_in, const int* in_sizes, int n_in,
                              void* d_out, int out_size, void* d_ws, size_t ws_size,
                              hipStream_t stream) {
    const float* query = (const float*)d_in[0];
    const float* key   = (const float*)d_in[1];
    const float* Wq    = (const float*)d_in[2];
    const float* bq    = (const float*)d_in[3];
    const float* Wk    = (const float*)d_in[4];
    const float* bk    = (const float*)d_in[5];
    const unsigned char* kpm = (const unsigned char*)d_in[6];
    const unsigned char* am  = (const unsigned char*)d_in[7];
    float* out = (float*)d_out;

    char* ws = (char*)d_ws;
    bf16_t* qin = (bf16_t*)(ws);                              //  8 MiB  [8192][512]
    bf16_t* kin = (bf16_t*)(ws + (8u << 20));                 //  8 MiB
    bf16_t* wqt = (bf16_t*)(ws + (16u << 20));                //  256 KiB [256][512]
    bf16_t* wkt = (bf16_t*)(ws + (16u << 20) + (256u << 10)); //  256 KiB
    bf16_t* Qb  = (bf16_t*)(ws + (17u << 20));                //  4 MiB  [hb][2048][32]
    bf16_t* Kb  = (bf16_t*)(ws + (21u << 20));                //  4 MiB
    int* flag   = (int*)(ws + (25u << 20));

    hipMemsetAsync(flag, 0, 4, stream);
    prep_qpe<<<2048, 256, 0, stream>>>(query, qin);
    prep_kcast<<<4096, 256, 0, stream>>>(key, kin);
    prep_wt<<<1024, 256, 0, stream>>>(Wq, Wk, wqt, wkt);
    mask_any<<<1026, 256, 0, stream>>>((const uint4*)am, (const uint4*)kpm, flag);
    proj_gemm<<<dim3(128, 4), 256, 0, stream>>>(qin, wqt, bq, Qb);
    proj_gemm<<<dim3(128, 4), 256, 0, stream>>>(kin, wkt, bk + 256, Kb);
    attn_kernel<<<dim3(32, 32), 256, 0, stream>>>(Qb, Kb, am, kpm, flag, out);
}